// Round 3
// baseline (266.399 us; speedup 1.0000x reference)
//
#include <hip/hip_runtime.h>

#define NCLS   100000
#define FEAT   192
#define F4     48          // FEAT/4
#define WP     49          // padded LDS pitch in float4 (odd -> conflict-free b128)
#define TILE   64
#define NB     512
#define NT     ((NCLS + TILE - 1)/TILE)   // 1563

// workspace layout (float offsets)
#define XN_OFF   0         // 6144
#define CM_OFF   6144      // cos(m_i)
#define SM_OFF   6176      // sin(m_i)
#define TH_OFF   6208      // cos(pi - m_i)
#define MM_OFF   6240      // sin(pi - m_i)*m_i
#define RG_OFF   6272      // 0.07*(nc-60)^2
#define LV_OFF   6304      // float(gt_label[s])
#define TGT_OFF  6336      // 1024: tgt[s][m] (natural-log domain)
#define CMAT_OFF 7360      // 1024: cost matrix C[s][m]
#define PART_OFF 8384      // 1024 pairs * NB blocks * float2  (4 MB)
// total ws use: ~4.03 MB

#define L2E30 43.2808512266689f       // 30*log2(e)
#define LN2   0.69314718055994531f

__device__ __forceinline__ float dot4(float4 a, float4 b){
  return fmaf(a.x,b.x, fmaf(a.y,b.y, fmaf(a.z,b.z, a.w*b.w)));
}
__device__ __forceinline__ void fma4(float4& a, float4 x, float4 w){
  a.x = fmaf(x.x,w.x,a.x); a.y = fmaf(x.y,w.y,a.y);
  a.z = fmaf(x.z,w.z,a.z); a.w = fmaf(x.w,w.w,a.w);
}
__device__ __forceinline__ float hsum4(float4 v){ return (v.x+v.y)+(v.z+v.w); }

// ---------------- K1: prep (xn, per-m params, lv, tgt) ----------------
__global__ __launch_bounds__(256) void k1_prep(const float* __restrict__ pe,
                                               const int* __restrict__ gt,
                                               const float* __restrict__ wgt,
                                               float* __restrict__ ws)
{
  __shared__ float4 PE4[1536];                 // pred_embs, then xn in-place
  __shared__ float INVN[32], CML[32], SML[32], THL[32], MML[32];
  const int tid = threadIdx.x;
  const float4* pe4 = (const float4*)pe;
  for (int i = tid; i < 1536; i += 256) PE4[i] = pe4[i];
  __syncthreads();

  const int m   = tid >> 3;
  const int sub = tid & 7;
  float ssq = 0.f;
  for (int j = 0; j < 6; ++j){ float4 v = PE4[m*F4 + sub + 8*j]; ssq += dot4(v,v); }
  ssq += __shfl_xor(ssq,1); ssq += __shfl_xor(ssq,2); ssq += __shfl_xor(ssq,4);
  float nrm = sqrtf(ssq);
  if (sub == 0){
    INVN[m] = 1.f / fmaxf(nrm, 1e-12f);
    float nc = fminf(fmaxf(nrm, 10.f), 110.f);
    float mi = fmaf(0.01f, nc, 100.f/nc);
    const float pi = 3.14159265358979323846f;
    float cmv = cosf(mi), smv = sinf(mi);
    float thv = cosf(pi - mi);
    float mmv = sinf(pi - mi)*mi;
    CML[m]=cmv; SML[m]=smv; THL[m]=thv; MML[m]=mmv;
    ws[CM_OFF+m]=cmv; ws[SM_OFF+m]=smv; ws[TH_OFF+m]=thv; ws[MM_OFF+m]=mmv;
    float dr = nc - 60.f;
    ws[RG_OFF+m] = 0.07f*dr*dr;              // GAMMA*LMBDA*0.01 = 0.07
  }
  if (tid < 32) ws[LV_OFF+tid] = (float)gt[tid];
  __syncthreads();

  float* PEf = (float*)PE4;
  for (int i = tid; i < 6144; i += 256){
    float v = PEf[i] * INVN[i/FEAT];
    PEf[i] = v;                               // xn in-place
    ws[XN_OFF+i] = v;
  }
  __syncthreads();

  // tgt[s][m]: 8 threads per s, gt row kept in registers
  const int s  = tid >> 3;
  const int cs = gt[s];
  const float4* gw4 = (const float4*)wgt;
  float4 wreg[6];
  float wsq = 0.f;
  for (int j = 0; j < 6; ++j){
    wreg[j] = gw4[(long)cs*F4 + sub + 8*j];
    wsq += dot4(wreg[j], wreg[j]);
  }
  wsq += __shfl_xor(wsq,1); wsq += __shfl_xor(wsq,2); wsq += __shfl_xor(wsq,4);
  float invw = 1.f / fmaxf(sqrtf(wsq), 1e-12f);
  float lvv = (float)cs;
  for (int mm2 = 0; mm2 < 32; ++mm2){
    float dp = 0.f;
    for (int j = 0; j < 6; ++j) dp += dot4(PE4[mm2*F4 + sub + 8*j], wreg[j]);
    dp += __shfl_xor(dp,1); dp += __shfl_xor(dp,2); dp += __shfl_xor(dp,4);
    if (sub == 0){
      float c = dp * invw;
      float sine = sqrtf(fminf(fmaxf(1.f - c*c, 0.f), 1.f));
      float phi = c*CML[mm2] - sine*SML[mm2];
      phi = (c > THL[mm2]) ? phi : (c - MML[mm2]);
      ws[TGT_OFF + s*32 + mm2] = fmaf(30.f*lvv, phi - c, 30.f*c);
    }
  }
}

// ---------------- K2: main fused GEMM + online logsumexp ----------------
__global__ __launch_bounds__(256, 2) void k2_main(const float* __restrict__ wgt,
                                                  const float* wsr,
                                                  float2* part)
{
  __shared__ float4 W4[TILE*WP];   // 3136 f4 = 49KB ; OB/OS alias into it
  __shared__ float4 XN4[32*F4];    // 1536 f4 = 24KB
  float4* OB4 = W4;                // [64 classes][8 mg]
  float4* OS4 = W4 + 512;
  const int tid = threadIdx.x;
  const float4* gw4 = (const float4*)wgt;
  const float4* xns = (const float4*)(wsr + XN_OFF);
  for (int i = tid; i < 1536; i += 256) XN4[i] = xns[i];

  const int cls = tid & 31;        // class slot (also s for accumulate phase)
  const int mg  = tid >> 5;        // m-group: m = 4*mg + q
  float cm[4], sm[4], thv[4], mmv[4];
#pragma unroll
  for (int q = 0; q < 4; ++q){
    int m = 4*mg + q;
    cm[q]=wsr[CM_OFF+m]; sm[q]=wsr[SM_OFF+m]; thv[q]=wsr[TH_OFF+m]; mmv[q]=wsr[MM_OFF+m];
  }
  const float lvs = wsr[LV_OFF + cls];
  float mx[4], sums[4];
#pragma unroll
  for (int q = 0; q < 4; ++q){ mx[q] = -1e30f; sums[q] = 0.f; }
  __syncthreads();

  for (int t = blockIdx.x; t < NT; t += NB){
    const int c0 = t*TILE;
    const int nv  = (NCLS - c0 < TILE) ? (NCLS - c0) : TILE;
    const int nf4 = nv*F4;
#pragma unroll
    for (int r = 0; r < 12; ++r){
      int idx = tid + 256*r;
      if (idx < nf4){
        int cc = idx/F4;
        int kk = idx - cc*F4;
        W4[cc*WP + kk] = gw4[(long)c0*F4 + idx];
      }
    }
    __syncthreads();

    float4 acc[4][2], nsq[2];
#pragma unroll
    for (int q = 0; q < 4; ++q){ acc[q][0]=make_float4(0,0,0,0); acc[q][1]=make_float4(0,0,0,0); }
    nsq[0]=make_float4(0,0,0,0); nsq[1]=make_float4(0,0,0,0);
#pragma unroll 4
    for (int k4 = 0; k4 < F4; ++k4){
      float4 w0 = W4[cls*WP + k4];
      float4 w1 = W4[(cls+32)*WP + k4];
      fma4(nsq[0], w0, w0);
      fma4(nsq[1], w1, w1);
#pragma unroll
      for (int q = 0; q < 4; ++q){
        float4 xv = XN4[(4*mg+q)*F4 + k4];   // half-wave broadcast
        fma4(acc[q][0], xv, w0);
        fma4(acc[q][1], xv, w1);
      }
    }
    __syncthreads();   // done reading W tile

#pragma unroll
    for (int ci = 0; ci < 2; ++ci){
      float invn = rsqrtf(fmaxf(hsum4(nsq[ci]), 1e-24f));
      float obv[4], osv[4];
#pragma unroll
      for (int q = 0; q < 4; ++q){
        float c = hsum4(acc[q][ci]) * invn;
        float sine = sqrtf(fminf(fmaxf(1.f - c*c, 0.f), 1.f));
        float phi = c*cm[q] - sine*sm[q];
        phi = (c > thv[q]) ? phi : (c - mmv[q]);
        obv[q] = L2E30 * c;
        osv[q] = L2E30 * (phi - c);
      }
      OB4[(cls + 32*ci)*8 + mg] = make_float4(obv[0],obv[1],obv[2],obv[3]);
      OS4[(cls + 32*ci)*8 + mg] = make_float4(osv[0],osv[1],osv[2],osv[3]);
    }
    __syncthreads();

    for (int ci = 0; ci < nv; ++ci){
      float4 ob = OB4[ci*8 + mg];
      float4 os = OS4[ci*8 + mg];
      float ov[4] = { fmaf(lvs, os.x, ob.x), fmaf(lvs, os.y, ob.y),
                      fmaf(lvs, os.z, ob.z), fmaf(lvs, os.w, ob.w) };
#pragma unroll
      for (int q = 0; q < 4; ++q){
        float d2 = ov[q] - mx[q];
        if (d2 > 0.f){ sums[q] = fmaf(sums[q], exp2f(-d2), 1.f); mx[q] = ov[q]; }
        else if (d2 > -28.f) sums[q] += exp2f(d2);
      }
    }
    __syncthreads();   // protect OB/OS (aliases W) before next stage
  }
#pragma unroll
  for (int q = 0; q < 4; ++q){
    int pp = cls*32 + 4*mg + q;      // pair = s*32 + m
    part[(long)pp*NB + blockIdx.x] = make_float2(mx[q], sums[q]);
  }
}

// ---------------- K3: combine partials -> cost matrix ----------------
__global__ __launch_bounds__(64) void k3_reduce(const float2* part, float* ws)
{
  const int p = blockIdx.x;
  const int l = threadIdx.x;
  float M = -1e30f, S = 0.f;
  for (int r = 0; r < NB/64; ++r){
    float2 v = part[(long)p*NB + l + 64*r];
    float M2 = fmaxf(M, v.x);
    S = S*exp2f(M - M2) + v.y*exp2f(v.x - M2);
    M = M2;
  }
  for (int k = 1; k < 64; k <<= 1){
    float Mo = __shfl_xor(M, k);
    float So = __shfl_xor(S, k);
    float M2 = fmaxf(M, Mo);
    S = S*exp2f(M - M2) + So*exp2f(Mo - M2);
    M = M2;
  }
  if (l == 0){
    float lse = LN2*(M + log2f(S));
    ws[CMAT_OFF + p] = lse - ws[TGT_OFF + p] + ws[RG_OFF + (p & 31)];
  }
}

// ---------------- K4: wave-parallel Hungarian + final scalar ----------------
__global__ __launch_bounds__(64) void k4_final(const float* __restrict__ psin,
                                               const float* __restrict__ wsr,
                                               float* __restrict__ out)
{
  __shared__ float CL[1024];
  const int l = threadIdx.x;
  for (int i = l; i < 1024; i += 64) CL[i] = wsr[CMAT_OFF + i];
  __syncthreads();

  // lane l <-> column j = l+1 (lanes >=32 inert)
  float v = 0.f, uu = 0.f;     // v[j], u[p[j]]
  int p = 0, way = 0;
  for (int i = 1; i <= 32; ++i){
    float minv = 1e30f;
    int used = (l < 32) ? 0 : 1;
    way = 0;
    float uu0 = 0.f;           // u[i] of current row (column 0 is virtual)
    int j0 = 0;
    for (int guard = 0; guard < 64; ++guard){
      if (j0 > 0 && l == j0-1) used = 1;
      int i0; float u0;
      if (j0 == 0){ i0 = i; u0 = uu0; }
      else { i0 = __shfl(p, j0-1); u0 = __shfl(uu, j0-1); }
      float cst = CL[(i0-1)*32 + (l & 31)];
      float cur = cst - u0 - v;
      if (!used && cur < minv){ minv = cur; way = j0; }
      float mval = used ? 1e30f : minv;
      float dmin = mval;
      for (int k = 1; k < 64; k <<= 1) dmin = fminf(dmin, __shfl_xor(dmin, k));
      unsigned long long b = __ballot(mval == dmin);
      int j1 = __builtin_ctzll(b) + 1;      // first (lowest j) argmin = ref tie-break
      float delta = dmin;
      if (used){ uu += delta; v -= delta; } else { minv -= delta; }
      uu0 += delta;
      int pn = __shfl(p, j1-1);
      j0 = j1;
      if (pn == 0) break;
    }
    // augment along 'way' chain
    for (int guard = 0; guard < 40 && j0 != 0; ++guard){
      int jw = __shfl(way, j0-1);
      int pp_; float pu;
      if (jw == 0){ pp_ = i; pu = uu0; }
      else { pp_ = __shfl(p, jw-1); pu = __shfl(uu, jw-1); }
      if (l == j0-1){ p = pp_; uu = pu; }
      j0 = jw;
    }
  }
  // L_spk: mean of C[p[j]-1][j-1] over 32 columns
  float csum = 0.f;
  if (l < 32) csum = CL[(p-1)*32 + l];
  for (int k = 1; k < 64; k <<= 1) csum += __shfl_xor(csum, k);
  // L_exist: t_exist == 1 for all (square assignment) -> mean(-log p)
  float lex = 0.f;
  if (l < 32){
    float pv = psin[l];
    pv = fminf(fmaxf(pv, 1e-6f), 1.f - 1e-6f);
    lex = -logf(pv);
  }
  for (int k = 1; k < 64; k <<= 1) lex += __shfl_xor(lex, k);
  if (l == 0)
    out[0] = csum/32.f + 100.f*(lex/32.f) + 100.f*0.69314718055994531f; // + XI*L_stop
}

extern "C" void kernel_launch(void* const* d_in, const int* in_sizes, int n_in,
                              void* d_out, int out_size, void* d_ws, size_t ws_size,
                              hipStream_t stream)
{
  (void)in_sizes; (void)n_in; (void)out_size; (void)ws_size;
  const float* pe  = (const float*)d_in[0];
  const float* ps  = (const float*)d_in[1];
  const int*   gt  = (const int*)  d_in[2];
  const float* wgt = (const float*)d_in[3];
  float* ws  = (float*)d_ws;
  float* out = (float*)d_out;
  hipLaunchKernelGGL(k1_prep,   dim3(1),    dim3(256), 0, stream, pe, gt, wgt, ws);
  hipLaunchKernelGGL(k2_main,   dim3(NB),   dim3(256), 0, stream, wgt, ws,
                     (float2*)(ws + PART_OFF));
  hipLaunchKernelGGL(k3_reduce, dim3(1024), dim3(64),  0, stream,
                     (const float2*)(ws + PART_OFF), ws);
  hipLaunchKernelGGL(k4_final,  dim3(1),    dim3(64),  0, stream, ps, ws, out);
}